// Round 1
// baseline (153.383 us; speedup 1.0000x reference)
//
#include <hip/hip_runtime.h>

// BinStats: per-channel searchsorted histogram.
//   x:(B=64, C=512, H=28, W=28) f32, bin_edges:(512,11), feature_ranges:(512,1),
//   bin_counts:(512,10). out[c][j] = bin_counts[c][j] + #{elements of channel c in bin j}
//   where bin j = searchsorted(inner_edges(9), x/range, side='left').
//
// Design (memory-bound, 102.8 MB read):
//  - one block per channel (512 blocks x 1024 threads): edges are wave-uniform,
//    per-thread register counters stay channel-pure, no global atomics needed.
//  - counters t[j] = count(x > edge_j * range): searchsorted-left folded into
//    9 branchless compare-adds; hist[j] = t[j-1] - t[j] by sortedness of edges.
//  - range folded into edges once per block (e_j*r < x  <=>  e_j < x/r, r>0).
//  - float4 loads: 784 floats per (b,c) slab => each float4 is channel-pure.

#define N_CH    512
#define HW      784            // 28*28
#define NB      64             // batch
#define F4_PER_SLAB 196        // HW/4
#define NF4     (NB * F4_PER_SLAB)  // float4s per channel = 12544
#define BLK     1024
#define TOTAL_PER_CH (NB * HW) // 50176

__global__ __launch_bounds__(BLK, 2) void binstats_kernel(
    const float* __restrict__ x,
    const float* __restrict__ bin_edges,      // (512, 11)
    const float* __restrict__ feature_ranges, // (512,)
    const float* __restrict__ bin_counts,     // (512, 10)
    float* __restrict__ out)                  // (512, 10)
{
    const int c   = blockIdx.x;
    const int tid = threadIdx.x;

    __shared__ unsigned t_sh[9];
    if (tid < 9) t_sh[tid] = 0u;

    // Per-channel scaled inner edges (uniform across block -> s_load + SGPRs).
    const float r = feature_ranges[c];
    float e[9];
#pragma unroll
    for (int j = 0; j < 9; ++j) e[j] = bin_edges[c * 11 + 1 + j] * r;

    __syncthreads();

    unsigned t[9];
#pragma unroll
    for (int j = 0; j < 9; ++j) t[j] = 0u;

    const float4* xf4 = (const float4*)x;
    // float4 index i within this channel: batch b = i/196, pos = i%196
    for (int i = tid; i < NF4; i += BLK) {
        const int b   = i / F4_PER_SLAB;           // magic-mul, constant divisor
        const int pos = i - b * F4_PER_SLAB;
        const float4 v = xf4[b * (N_CH * F4_PER_SLAB) + c * F4_PER_SLAB + pos];
#pragma unroll
        for (int j = 0; j < 9; ++j) {
            t[j] += (unsigned)(v.x > e[j]);
            t[j] += (unsigned)(v.y > e[j]);
            t[j] += (unsigned)(v.z > e[j]);
            t[j] += (unsigned)(v.w > e[j]);
        }
    }

    // Wave-level reduce (64 lanes), then one LDS atomic per wave per counter.
#pragma unroll
    for (int j = 0; j < 9; ++j) {
        unsigned v = t[j];
        for (int off = 32; off > 0; off >>= 1)
            v += __shfl_down(v, off, 64);
        if ((tid & 63) == 0) atomicAdd(&t_sh[j], v);
    }
    __syncthreads();

    // hist[0] = N - t[0]; hist[j] = t[j-1] - t[j]; hist[9] = t[8]
    if (tid < 10) {
        unsigned h;
        if (tid == 0)       h = (unsigned)TOTAL_PER_CH - t_sh[0];
        else if (tid == 9)  h = t_sh[8];
        else                h = t_sh[tid - 1] - t_sh[tid];
        out[c * 10 + tid] = bin_counts[c * 10 + tid] + (float)h;
    }
}

extern "C" void kernel_launch(void* const* d_in, const int* in_sizes, int n_in,
                              void* d_out, int out_size, void* d_ws, size_t ws_size,
                              hipStream_t stream) {
    const float* x  = (const float*)d_in[0];
    const float* be = (const float*)d_in[1];
    const float* fr = (const float*)d_in[2];
    const float* bc = (const float*)d_in[3];
    float* out = (float*)d_out;

    binstats_kernel<<<N_CH, BLK, 0, stream>>>(x, be, fr, bc, out);
}